// Round 1
// baseline (2551.839 us; speedup 1.0000x reference)
//
#include <hip/hip_runtime.h>
#include <cstdint>
#include <cstddef>

#define SEQ 128
#define BATCH 64
#define EMBD 512
#define HIDD 512
#define NVOCAB 10000

typedef __attribute__((ext_vector_type(8))) short short8;
typedef __attribute__((ext_vector_type(4))) float f32x4;

__device__ __forceinline__ unsigned short f2b(float f) {
  union { float f; unsigned u; } c; c.f = f;
  unsigned u = c.u;
  unsigned r = (u + 0x7fffu + ((u >> 16) & 1u)) >> 16;
  return (unsigned short)r;
}

__device__ __forceinline__ f32x4 mfma16(short8 a, short8 b, f32x4 c) {
  return __builtin_amdgcn_mfma_f32_16x16x32_bf16(a, b, c, 0, 0, 0);
}

// ---------------- packing: src f32 (K x N row-major) -> frag-linear bf16 ----
// dst[ntile][kstep][lane][8] ; value = src[row_off + ks*32 + (l>>4)*8 + j][colmap(ntile*16 + (l&15))]
// mode 0: col = n (0-pad if n >= nreal). mode 1: packed gate cols (u|r interleave per 16-col owner)
__global__ void pack_frag(const float* __restrict__ src, unsigned short* __restrict__ dst,
                          int ksteps, int row_off, int src_ld, int ntiles, int mode, int nreal) {
  int tid = blockIdx.x * 256 + threadIdx.x;
  int total = ntiles * ksteps * 64;
  if (tid >= total) return;
  int l = tid & 63;
  int ks = (tid >> 6) % ksteps;
  int nt = tid / (64 * ksteps);
  int n = nt * 16 + (l & 15);
  int col;
  bool valid = true;
  if (mode == 1) {
    int jc = n >> 5, s = n & 31;
    col = (s < 16) ? (16 * jc + s) : (512 + 16 * jc + (s - 16));
  } else {
    col = n;
    valid = (n < nreal);
  }
  int k0 = row_off + ks * 32 + ((l >> 4) << 3);
  short8 o;
  for (int j = 0; j < 8; ++j) {
    float x = valid ? src[(size_t)(k0 + j) * src_ld + col] : 0.f;
    o[j] = (short)f2b(x);
  }
  *reinterpret_cast<short8*>(&dst[(size_t)tid * 8]) = o;
}

__global__ void pack_bias(const float* __restrict__ bg0, const float* __restrict__ bg1,
                          float* __restrict__ bg0p, float* __restrict__ bg1p) {
  int p = blockIdx.x * 256 + threadIdx.x;
  if (p >= 1024) return;
  int jc = p >> 5, s = p & 31;
  int col = (s < 16) ? (16 * jc + s) : (512 + 16 * jc + (s - 16));
  bg0p[p] = bg0[col];
  bg1p[p] = bg1[col];
}

// ------------- embedding gather into kmat layout [t][ktile][row][8] bf16 ----
__global__ void embed_gather(const int* __restrict__ inp, const float* __restrict__ tab,
                             unsigned short* __restrict__ XA) {
  int tid = blockIdx.x * 256 + threadIdx.x; // ((t*64 + kt)*64 + row)
  if (tid >= SEQ * 64 * 64) return;
  int row = tid & 63;
  int kt = (tid >> 6) & 63;
  int t = tid >> 12;
  int v = inp[t * BATCH + row];
  const float* s = &tab[(size_t)v * EMBD + kt * 8];
  const float scale = 22.627416997969522f; // sqrt(512)
  short8 o;
  for (int j = 0; j < 8; ++j) o[j] = (short)f2b(s[j] * scale);
  *reinterpret_cast<short8*>(&XA[(size_t)tid * 8]) = o;
}

// ------------- init states from input hidden ----
__global__ void init_states(const float* __restrict__ hid, float* __restrict__ H0F,
                            float* __restrict__ H1F, unsigned short* __restrict__ H0B1,
                            unsigned short* __restrict__ H1INITB) {
  int idx = blockIdx.x * 256 + threadIdx.x;
  if (idx >= 64 * 512) return;
  int row = idx >> 9, c = idx & 511;
  float h0 = hid[idx];
  float h1 = hid[64 * 512 + idx];
  H0F[idx] = h0; H1F[idx] = h1;
  size_t ko = (((size_t)(c >> 3)) * 64 + row) * 8 + (c & 7);
  H0B1[ko] = f2b(h0);
  H1INITB[ko] = f2b(h1);
}

// ------------- generic 128x128 LDS-tiled bf16 GEMM, K=512 ----
// A: kmat [Mblocks of 64 rows][64 ktiles][64 row][8] bf16. Bf: frag-linear. C: f32 row-major.
__launch_bounds__(256, 2)
__global__ void gemm128(const unsigned short* __restrict__ A, const unsigned short* __restrict__ Bf,
                        const float* __restrict__ bias, float* __restrict__ C,
                        int Nld, int Nreal) {
  __shared__ __align__(16) unsigned short ldsA[16 * 512];
  __shared__ __align__(16) unsigned short ldsB[16 * 512];
  int nb = blockIdx.x, yb = blockIdx.y;
  int l = threadIdx.x & 63, w = threadIdx.x >> 6;
  int mh = w >> 1, nh = w & 1;
  f32x4 acc[4][4] = {};
  for (int ko = 0; ko < 8; ++ko) {
    __syncthreads();
    for (int j = 0; j < 4; ++j) {
      int c = w * 4 + j;
      // A chunk c = m8*2 + ks
      int m8 = c >> 1, ks = c & 1;
      int t = yb * 2 + (m8 >> 2);
      int kt = ko * 8 + ks * 4 + (l >> 4);
      int row = (m8 & 3) * 16 + (l & 15);
      size_t g = (((size_t)t * 64 + kt) * 64 + row) * 8;
      *reinterpret_cast<short8*>(&ldsA[(size_t)c * 512 + l * 8]) =
          *reinterpret_cast<const short8*>(&A[g]);
      // B chunk c = nt*2 + ks
      size_t gb = (((size_t)(nb * 8 + (c >> 1)) * 16) + (size_t)(ko * 2 + (c & 1))) * 512 + (size_t)l * 8;
      *reinterpret_cast<short8*>(&ldsB[(size_t)c * 512 + l * 8]) =
          *reinterpret_cast<const short8*>(&Bf[gb]);
    }
    __syncthreads();
    for (int ks = 0; ks < 2; ++ks) {
      short8 a[4], b[4];
      for (int mt = 0; mt < 4; ++mt) {
        int m8 = mh * 4 + mt;
        a[mt] = *reinterpret_cast<const short8*>(&ldsA[((size_t)(m8 * 2 + ks) * 64 + l) * 8]);
      }
      for (int nt = 0; nt < 4; ++nt) {
        int n8 = nh * 4 + nt;
        b[nt] = *reinterpret_cast<const short8*>(&ldsB[((size_t)(n8 * 2 + ks) * 64 + l) * 8]);
      }
      for (int mt = 0; mt < 4; ++mt)
        for (int nt = 0; nt < 4; ++nt)
          acc[mt][nt] = mfma16(a[mt], b[nt], acc[mt][nt]);
    }
  }
  for (int mt = 0; mt < 4; ++mt) {
    for (int nt = 0; nt < 4; ++nt) {
      int col = nb * 128 + nh * 64 + nt * 16 + (l & 15);
      if (col >= Nreal) continue;
      float bv = bias[col];
      int row0 = yb * 128 + mh * 64 + mt * 16 + ((l >> 4) << 2);
      for (int r = 0; r < 4; ++r)
        C[(size_t)(row0 + r) * Nld + col] = acc[mt][nt][r] + bv;
    }
  }
}

// ------------- recurrence phase A: gates for L0(step i) and L1(step i-1) ----
// 64 WGs = (jc 0..31 col-owner of 16 cols) x (jr 0..1 row-half). waves: w0 g0u, w1 g0r, w2 g1u, w3 g1r
__global__ void rnn_A(int i, const float* __restrict__ Xg0p, const float* __restrict__ bg1p,
                      const unsigned short* __restrict__ Wg0h, const unsigned short* __restrict__ Wg1,
                      const unsigned short* __restrict__ H0B,
                      const unsigned short* __restrict__ H1ALL, const unsigned short* __restrict__ H1INITB,
                      const float* __restrict__ H0F, const float* __restrict__ H1F,
                      float* __restrict__ UBUF0, float* __restrict__ UBUF1,
                      unsigned short* __restrict__ RH0, unsigned short* __restrict__ RH1) {
  int jc = blockIdx.x & 31, jr = blockIdx.x >> 5;
  int l = threadIdx.x & 63, w = threadIdx.x >> 6;
  int layer = w >> 1, isr = w & 1;
  if (layer == 0 && i >= 128) return;
  if (layer == 1 && i < 1) return;
  int t0 = i, t1 = i - 1;
  const unsigned short* h0b = H0B + ((size_t)((i + 1) & 1)) * 32768; // h0 state (i-1), bf16 kmat
  int s = l & 15, q = l >> 4;
  f32x4 acc[2];
  if (layer == 0) {
    int p = jc * 32 + isr * 16 + s;
    for (int mt = 0; mt < 2; ++mt) {
      int row0 = jr * 32 + mt * 16 + q * 4;
      for (int r = 0; r < 4; ++r)
        acc[mt][r] = Xg0p[(size_t)(t0 * 64 + row0 + r) * 1024 + p];
    }
    const unsigned short* bf = Wg0h + ((size_t)(2 * jc + isr) * 16) * 512;
    for (int ks = 0; ks < 16; ++ks) {
      short8 b = *reinterpret_cast<const short8*>(&bf[(size_t)ks * 512 + l * 8]);
      for (int mt = 0; mt < 2; ++mt) {
        int row = jr * 32 + mt * 16 + s;
        short8 a = *reinterpret_cast<const short8*>(&h0b[(((size_t)(ks * 4 + q)) * 64 + row) * 8]);
        acc[mt] = mfma16(a, b, acc[mt]);
      }
    }
  } else {
    int p = jc * 32 + isr * 16 + s;
    float bv = bg1p[p];
    acc[0] = f32x4{bv, bv, bv, bv};
    acc[1] = acc[0];
    const unsigned short* bf = Wg1 + ((size_t)(2 * jc + isr) * 32) * 512;
    const unsigned short* h1src = (t1 >= 1) ? (H1ALL + (size_t)(t1 - 1) * 32768) : H1INITB;
    for (int ks = 0; ks < 32; ++ks) {
      short8 b = *reinterpret_cast<const short8*>(&bf[(size_t)ks * 512 + l * 8]);
      const unsigned short* asrc = (ks < 16) ? h0b : h1src;
      int kk = ks & 15;
      for (int mt = 0; mt < 2; ++mt) {
        int row = jr * 32 + mt * 16 + s;
        short8 a = *reinterpret_cast<const short8*>(&asrc[(((size_t)(kk * 4 + q)) * 64 + row) * 8]);
        acc[mt] = mfma16(a, b, acc[mt]);
      }
    }
  }
  float* ubuf = (layer == 0) ? UBUF0 : UBUF1;
  const float* hf = (layer == 0) ? H0F : H1F;
  unsigned short* rh = (layer == 0) ? RH0 : RH1;
  int c = 16 * jc + s;
  for (int mt = 0; mt < 2; ++mt) {
    int row0 = jr * 32 + mt * 16 + q * 4;
    for (int r = 0; r < 4; ++r) {
      float g = 1.f / (1.f + __expf(-acc[mt][r]));
      int row = row0 + r;
      if (!isr) {
        ubuf[(size_t)row * 512 + c] = g;
      } else {
        float rhv = g * hf[(size_t)row * 512 + c];
        rh[(((size_t)(c >> 3)) * 64 + row) * 8 + (c & 7)] = f2b(rhv);
      }
    }
  }
}

// ------------- recurrence phase B: cells + state update ----
// waves: w0 c0/M0, w1 c0/M1, w2 c1/M0, w3 c1/M1
__global__ void rnn_B(int i, const float* __restrict__ Xc0p, const float* __restrict__ bc1,
                      const unsigned short* __restrict__ Wc0h, const unsigned short* __restrict__ Wc1,
                      unsigned short* __restrict__ H0B,
                      const unsigned short* __restrict__ RH0, const unsigned short* __restrict__ RH1,
                      const float* __restrict__ UBUF0, const float* __restrict__ UBUF1,
                      float* __restrict__ H0F, float* __restrict__ H1F,
                      unsigned short* __restrict__ H1ALL) {
  int jc = blockIdx.x & 31, jr = blockIdx.x >> 5;
  int l = threadIdx.x & 63, w = threadIdx.x >> 6;
  int layer = w >> 1, mt = w & 1;
  if (layer == 0 && i >= 128) return;
  if (layer == 1 && i < 1) return;
  int t0 = i, t1 = i - 1;
  int s = l & 15, q = l >> 4;
  int rowb = jr * 32 + mt * 16;
  f32x4 acc;
  if (layer == 0) {
    for (int r = 0; r < 4; ++r)
      acc[r] = Xc0p[(size_t)(t0 * 64 + rowb + q * 4 + r) * 512 + 16 * jc + s];
    const unsigned short* bf = Wc0h + (size_t)jc * 16 * 512;
    for (int ks = 0; ks < 16; ++ks) {
      short8 b = *reinterpret_cast<const short8*>(&bf[(size_t)ks * 512 + l * 8]);
      short8 a = *reinterpret_cast<const short8*>(&RH0[(((size_t)(ks * 4 + q)) * 64 + rowb + s) * 8]);
      acc = mfma16(a, b, acc);
    }
  } else {
    float bv = bc1[16 * jc + s];
    acc = f32x4{bv, bv, bv, bv};
    const unsigned short* bf = Wc1 + (size_t)jc * 32 * 512;
    const unsigned short* h0prev = H0B + ((size_t)((i + 1) & 1)) * 32768; // h0 state (i-1)
    for (int ks = 0; ks < 32; ++ks) {
      short8 b = *reinterpret_cast<const short8*>(&bf[(size_t)ks * 512 + l * 8]);
      const unsigned short* asrc = (ks < 16) ? h0prev : RH1;
      int kk = ks & 15;
      short8 a = *reinterpret_cast<const short8*>(&asrc[(((size_t)(kk * 4 + q)) * 64 + rowb + s) * 8]);
      acc = mfma16(a, b, acc);
    }
  }
  int c = 16 * jc + s;
  const float* ubuf = (layer == 0) ? UBUF0 : UBUF1;
  float* hf = (layer == 0) ? H0F : H1F;
  for (int r = 0; r < 4; ++r) {
    int row = rowb + q * 4 + r;
    float cv = tanhf(acc[r]);
    float u = ubuf[(size_t)row * 512 + c];
    float hp = hf[(size_t)row * 512 + c];
    float hn = hp + u * (cv - hp);
    hf[(size_t)row * 512 + c] = hn;
    unsigned short hb = f2b(hn);
    size_t ko = (((size_t)(c >> 3)) * 64 + row) * 8 + (c & 7);
    if (layer == 0) H0B[((size_t)(i & 1)) * 32768 + ko] = hb;
    else            H1ALL[(size_t)t1 * 32768 + ko] = hb;
  }
}

__global__ void write_hidden(const float* __restrict__ H0F, const float* __restrict__ H1F,
                             float* __restrict__ out) {
  int idx = blockIdx.x * 256 + threadIdx.x;
  if (idx >= 32768) return;
  out[idx] = H0F[idx];
  out[32768 + idx] = H1F[idx];
}

static inline int gridFor(long long n) { return (int)((n + 255) / 256); }

extern "C" void kernel_launch(void* const* d_in, const int* in_sizes, int n_in,
                              void* d_out, int out_size, void* d_ws, size_t ws_size,
                              hipStream_t stream) {
  const int*   inputs = (const int*)d_in[0];
  const float* hidden = (const float*)d_in[1];
  const float* embtab = (const float*)d_in[2];
  const float* Wg0 = (const float*)d_in[3];
  const float* bg0 = (const float*)d_in[4];
  const float* Wc0 = (const float*)d_in[5];
  const float* bc0 = (const float*)d_in[6];
  const float* Wg1 = (const float*)d_in[7];
  const float* bg1 = (const float*)d_in[8];
  const float* Wc1 = (const float*)d_in[9];
  const float* bc1 = (const float*)d_in[10];
  const float* Wout = (const float*)d_in[11];
  const float* bout = (const float*)d_in[12];
  float* out = (float*)d_out;

  // ---- workspace carve ----
  char* p = (char*)d_ws;
  size_t off = 0;
  auto carve = [&](size_t bytes) { char* r = p + off; off += (bytes + 255) & ~(size_t)255; return (void*)r; };
  unsigned short* XA     = (unsigned short*)carve((size_t)8192 * 512 * 2);
  unsigned short* Wg0x_f = (unsigned short*)carve((size_t)512 * 1024 * 2);
  unsigned short* Wg0h_f = (unsigned short*)carve((size_t)512 * 1024 * 2);
  unsigned short* Wc0x_f = (unsigned short*)carve((size_t)512 * 512 * 2);
  unsigned short* Wc0h_f = (unsigned short*)carve((size_t)512 * 512 * 2);
  unsigned short* Wg1_f  = (unsigned short*)carve((size_t)1024 * 1024 * 2);
  unsigned short* Wc1_f  = (unsigned short*)carve((size_t)1024 * 512 * 2);
  unsigned short* Wout_f = (unsigned short*)carve((size_t)512 * 10240 * 2);
  float* Xg0p = (float*)carve((size_t)8192 * 1024 * 4);
  float* Xc0p = (float*)carve((size_t)8192 * 512 * 4);
  unsigned short* H1ALL  = (unsigned short*)carve((size_t)128 * 32768 * 2);
  unsigned short* H0B    = (unsigned short*)carve((size_t)2 * 32768 * 2);
  unsigned short* H1INITB= (unsigned short*)carve((size_t)32768 * 2);
  float* H0F = (float*)carve((size_t)32768 * 4);
  float* H1F = (float*)carve((size_t)32768 * 4);
  unsigned short* RH0 = (unsigned short*)carve((size_t)32768 * 2);
  unsigned short* RH1 = (unsigned short*)carve((size_t)32768 * 2);
  float* UBUF0 = (float*)carve((size_t)32768 * 4);
  float* UBUF1 = (float*)carve((size_t)32768 * 4);
  float* bg0p = (float*)carve(1024 * 4);
  float* bg1p = (float*)carve(1024 * 4);
  if (off > ws_size) return; // workspace too small: bail cleanly

  // ---- pack weights into fragment-linear bf16 ----
  pack_frag<<<gridFor(64LL * 16 * 64), 256, 0, stream>>>(Wg0, Wg0x_f, 16, 0,   1024, 64, 1, 1024);
  pack_frag<<<gridFor(64LL * 16 * 64), 256, 0, stream>>>(Wg0, Wg0h_f, 16, 512, 1024, 64, 1, 1024);
  pack_frag<<<gridFor(32LL * 16 * 64), 256, 0, stream>>>(Wc0, Wc0x_f, 16, 0,   512,  32, 0, 512);
  pack_frag<<<gridFor(32LL * 16 * 64), 256, 0, stream>>>(Wc0, Wc0h_f, 16, 512, 512,  32, 0, 512);
  pack_frag<<<gridFor(64LL * 32 * 64), 256, 0, stream>>>(Wg1, Wg1_f,  32, 0,   1024, 64, 1, 1024);
  pack_frag<<<gridFor(32LL * 32 * 64), 256, 0, stream>>>(Wc1, Wc1_f,  32, 0,   512,  32, 0, 512);
  pack_frag<<<gridFor(640LL * 16 * 64), 256, 0, stream>>>(Wout, Wout_f, 16, 0, 10000, 640, 0, 10000);
  pack_bias<<<4, 256, 0, stream>>>(bg0, bg1, bg0p, bg1p);

  // ---- embedding + state init ----
  embed_gather<<<gridFor((long long)SEQ * 64 * 64), 256, 0, stream>>>(inputs, embtab, XA);
  init_states<<<gridFor(32768), 256, 0, stream>>>(hidden, H0F, H1F, H0B + 32768, H1INITB);

  // ---- precompute x-parts of layer-0 gates/cell (big parallel GEMMs) ----
  gemm128<<<dim3(8, 64), 256, 0, stream>>>(XA, Wg0x_f, bg0p, Xg0p, 1024, 1024);
  gemm128<<<dim3(4, 64), 256, 0, stream>>>(XA, Wc0x_f, bc0, Xc0p, 512, 512);

  // ---- recurrence: 129 pipelined intervals (L0 step i, L1 step i-1) ----
  for (int i = 0; i <= 128; ++i) {
    rnn_A<<<64, 256, 0, stream>>>(i, Xg0p, bg1p, Wg0h_f, Wg1_f, H0B, H1ALL, H1INITB,
                                  H0F, H1F, UBUF0, UBUF1, RH0, RH1);
    rnn_B<<<64, 256, 0, stream>>>(i, Xc0p, bc1, Wc0h_f, Wc1_f, H0B, RH0, RH1,
                                  UBUF0, UBUF1, H0F, H1F, H1ALL);
  }

  // ---- logits: (8192x512) @ (512x10000) + bout -> d_out ----
  gemm128<<<dim3(80, 64), 256, 0, stream>>>(H1ALL, Wout_f, bout, out, 10000, 10000);

  // ---- final hidden state ----
  write_hidden<<<gridFor(32768), 256, 0, stream>>>(H0F, H1F, out + (size_t)81920000);
}